// Round 5
// baseline (290.875 us; speedup 1.0000x reference)
//
#include <hip/hip_runtime.h>
#include <cstdint>
#include <cstddef>

#define N_NODES 50000
#define N_EDGES 400000
#define E_TOT   (N_EDGES + N_NODES)   // with self-loops
#define D_INF   128
#define C1      256                   // 8 heads * 32
#define HIDC    32
#define OUTC    16
#define HEADS   8
#define SCAN_B  ((N_NODES + 1023) / 1024)   // 49 scan blocks

typedef __bf16 bf16x8 __attribute__((ext_vector_type(8)));
typedef float  floatx4 __attribute__((ext_vector_type(4)));
typedef unsigned int uintx4 __attribute__((ext_vector_type(4)));
typedef unsigned short ushortx8 __attribute__((ext_vector_type(8)));
typedef unsigned short ushortx4 __attribute__((ext_vector_type(4)));

__device__ __forceinline__ unsigned short f2bf(float f) {
  unsigned int u = __builtin_bit_cast(unsigned int, f);
  u += 0x7FFFu + ((u >> 16) & 1u);   // RNE (finite values)
  return (unsigned short)(u >> 16);
}
__device__ __forceinline__ float bf2f(unsigned short u) {
  return __builtin_bit_cast(float, (unsigned int)u << 16);
}

// ---------- edge_index word-width autodetect ----------
__global__ void k_detect(const int* __restrict__ ei, int* __restrict__ flag) {
  __shared__ int s;
  if (threadIdx.x == 0) s = 0;
  __syncthreads();
  atomicOr(&s, ei[2 * threadIdx.x + 1]);
  __syncthreads();
  if (threadIdx.x == 0) *flag = (s == 0) ? 1 : 0;   // 1 = int64
}
__device__ __forceinline__ int ld_src(const int* ei, int f, int e) {
  return f ? ei[2 * e] : ei[e];
}
__device__ __forceinline__ int ld_dst(const int* ei, int f, int e) {
  return f ? ei[2 * (N_EDGES + e)] : ei[N_EDGES + e];
}

// ---------- all 4 weight transposes in one launch (f32 -> bf16, [R][C]->[C][R]) ----------
__global__ void k_transpose_all(const float* __restrict__ W1l, const float* __restrict__ W1r,
                                const float* __restrict__ W2l, const float* __restrict__ W2r,
                                unsigned short* __restrict__ W1lT, unsigned short* __restrict__ W1rT,
                                unsigned short* __restrict__ W2lT, unsigned short* __restrict__ W2rT) {
  int i = blockIdx.x * 256 + threadIdx.x;
  const int S1 = D_INF * C1;          // 32768
  const int S2 = C1 * HIDC;           // 8192
  if (i < S1) {
    int r = i / C1, c = i % C1;
    W1lT[c * D_INF + r] = f2bf(W1l[i]);
  } else if (i < 2 * S1) {
    int j = i - S1; int r = j / C1, c = j % C1;
    W1rT[c * D_INF + r] = f2bf(W1r[j]);
  } else if (i < 2 * S1 + S2) {
    int j = i - 2 * S1; int r = j / HIDC, c = j % HIDC;
    W2lT[c * C1 + r] = f2bf(W2l[j]);
  } else if (i < 2 * S1 + 2 * S2) {
    int j = i - 2 * S1 - S2; int r = j / HIDC, c = j % HIDC;
    W2rT[c * C1 + r] = f2bf(W2r[j]);
  }
}

// ---------- CSR build ----------
__global__ void k_deg(const int* __restrict__ ei, const int* __restrict__ flag,
                      int* __restrict__ deg) {
  int e = blockIdx.x * 256 + threadIdx.x;
  if (e < E_TOT) {
    int dst = (e < N_EDGES) ? ld_dst(ei, *flag, e) : (e - N_EDGES);
    if ((unsigned)dst < N_NODES) atomicAdd(&deg[dst], 1);
  }
}

__global__ __launch_bounds__(1024) void k_scan_blk(
    const int* __restrict__ deg, int* __restrict__ incl,
    int* __restrict__ bsum, int n) {
  __shared__ int sbuf[1024];
  const int t = threadIdx.x;
  const int i = blockIdx.x * 1024 + t;
  const int v = (i < n) ? deg[i] : 0;
  sbuf[t] = v;
  __syncthreads();
  for (int off = 1; off < 1024; off <<= 1) {
    int add = (t >= off) ? sbuf[t - off] : 0;
    __syncthreads();
    sbuf[t] += add;
    __syncthreads();
  }
  if (i < n) incl[i] = sbuf[t];
  if (t == 1023) bsum[blockIdx.x] = sbuf[1023];
}

__global__ void k_scan_top(int* __restrict__ bsum, int* __restrict__ rowptr,
                           int nb) {   // nb <= 64, one wave
  const int lane = threadIdx.x;
  const int v = (lane < nb) ? bsum[lane] : 0;
  int incl = v;
#pragma unroll
  for (int off = 1; off < 64; off <<= 1) {
    int t = __shfl_up(incl, off);
    if (lane >= off) incl += t;
  }
  if (lane < nb) bsum[lane] = incl - v;   // exclusive block offset
  if (lane == 63) rowptr[N_NODES] = incl; // grand total
}

__global__ __launch_bounds__(1024) void k_scan_add(
    const int* __restrict__ deg, const int* __restrict__ incl,
    const int* __restrict__ bsum, int* __restrict__ rowptr,
    int* __restrict__ cursor, int n) {
  const int i = blockIdx.x * 1024 + threadIdx.x;
  if (i < n) {
    const int e = bsum[blockIdx.x] + incl[i] - deg[i];
    rowptr[i] = e;
    cursor[i] = e;
  }
}

__global__ void k_fill(const int* __restrict__ ei, const int* __restrict__ flag,
                       int* __restrict__ cursor, int* __restrict__ esrc) {
  int e = blockIdx.x * 256 + threadIdx.x;
  if (e < E_TOT) {
    int src, dst;
    if (e < N_EDGES) { src = ld_src(ei, *flag, e); dst = ld_dst(ei, *flag, e); }
    else             { src = dst = e - N_EDGES; }
    if ((unsigned)src < N_NODES && (unsigned)dst < N_NODES) {
      int pos = atomicAdd(&cursor[dst], 1);
      esrc[pos] = src;
    }
  }
}

// ---------- A-fragment loaders ----------
__device__ __forceinline__ bf16x8 load8(const unsigned short* p) {
  uintx4 raw = *reinterpret_cast<const uintx4*>(p);
  return __builtin_bit_cast(bf16x8, raw);
}
__device__ __forceinline__ bf16x8 load8(const float* p) {
  floatx4 a = *reinterpret_cast<const floatx4*>(p);
  floatx4 b = *reinterpret_cast<const floatx4*>(p + 4);
  ushortx8 u;
#pragma unroll
  for (int i = 0; i < 4; ++i) { u[i] = f2bf(a[i]); u[4 + i] = f2bf(b[i]); }
  return __builtin_bit_cast(bf16x8, u);
}

// ---------- dual MFMA bf16 GEMM, column-split across waves ----------
// block = 4 waves, all on the same 32 rows (r0 = blockIdx*32); wave w computes
// output (w>>1) over NT/2 column tiles starting at (w&1)*(NT/2).
// A rows are re-read by all 4 waves -> served by L1 after first touch.
template <int K, int NCOLS, typename AT>
__global__ __launch_bounds__(256) void k_gemm_dual(
    const AT* __restrict__ A,
    const unsigned short* __restrict__ BT0, const unsigned short* __restrict__ BT1,
    unsigned short* __restrict__ C0, unsigned short* __restrict__ C1_, int M) {
  const int wave = threadIdx.x >> 6;
  const int lane = threadIdx.x & 63;
  const int lo = lane & 15;   // m for A, n for B, col for C/D
  const int q  = lane >> 4;   // k-chunk quad
  const int r0 = blockIdx.x * 32;
  if (r0 >= M) return;
  const bool two = (r0 + 16) < M;
  constexpr int KB = K / 32;
  constexpr int NT = NCOLS / 16;
  constexpr int NTW = (NT >= 2) ? NT / 2 : 1;   // tiles per wave

  bf16x8 afrag[2][KB];
#pragma unroll
  for (int kb = 0; kb < KB; ++kb)
    afrag[0][kb] = load8(A + (size_t)(r0 + lo) * K + kb * 32 + q * 8);
  if (two) {
#pragma unroll
    for (int kb = 0; kb < KB; ++kb)
      afrag[1][kb] = load8(A + (size_t)(r0 + 16 + lo) * K + kb * 32 + q * 8);
  }

  const int out_id = wave >> 1;
  const int ntbase = (wave & 1) * NTW;
  const unsigned short* BT = out_id ? BT1 : BT0;
  unsigned short* C = out_id ? C1_ : C0;

#pragma unroll
  for (int nti = 0; nti < NTW; ++nti) {
    const int nt = ntbase + nti;
    floatx4 acc0 = {0.f, 0.f, 0.f, 0.f};
    floatx4 acc1 = {0.f, 0.f, 0.f, 0.f};
    const unsigned short* bptr = BT + (size_t)(nt * 16 + lo) * K + q * 8;
#pragma unroll
    for (int kb = 0; kb < KB; ++kb) {
      bf16x8 b = load8(bptr + kb * 32);
      acc0 = __builtin_amdgcn_mfma_f32_16x16x32_bf16(afrag[0][kb], b, acc0, 0, 0, 0);
      if (two)
        acc1 = __builtin_amdgcn_mfma_f32_16x16x32_bf16(afrag[1][kb], b, acc1, 0, 0, 0);
    }
    // C/D layout: col = lane&15, row = (lane>>4)*4 + reg   [m89-verified]
#pragma unroll
    for (int r = 0; r < 4; ++r) {
      C[(size_t)(r0 + q * 4 + r) * NCOLS + nt * 16 + lo] = f2bf(acc0[r]);
      if (two)
        C[(size_t)(r0 + 16 + q * 4 + r) * NCOLS + nt * 16 + lo] = f2bf(acc1[r]);
    }
  }
}

// ---------- A-side attention dots: A1[n][h] = sum_c att1[h][c] * xl1[n][c] ----------
// half-wave (32 lanes) per node, 8 ch/lane; block 256 = 8 nodes.
__global__ __launch_bounds__(256) void k_att_pre1(
    const unsigned short* __restrict__ xl1, const float* __restrict__ att1,
    float* __restrict__ A1) {
  const int wave = threadIdx.x >> 6;
  const int lane = threadIdx.x & 63;
  const int h = lane >> 5;
  const int w = lane & 31;
  const int cb = w * 8;
  const int node = blockIdx.x * 8 + wave * 2 + h;
  if (node >= N_NODES) return;
  ushortx8 r = *reinterpret_cast<const ushortx8*>(xl1 + (size_t)node * C1 + cb);
  floatx4 a0 = *reinterpret_cast<const floatx4*>(att1 + cb);
  floatx4 a1 = *reinterpret_cast<const floatx4*>(att1 + cb + 4);
  float t = 0.f;
#pragma unroll
  for (int c = 0; c < 4; ++c) t = fmaf(bf2f(r[c]), a0[c], t);
#pragma unroll
  for (int c = 0; c < 4; ++c) t = fmaf(bf2f(r[4 + c]), a1[c], t);
  t += __shfl_xor(t, 1);
  t += __shfl_xor(t, 2);
  if ((w & 3) == 0) A1[node * HEADS + (w >> 2)] = t;
}

// A2[n] = sum_c att2[c] * xl2[n][c]; 8 lanes per node (4 ch each); block = 32 nodes.
__global__ __launch_bounds__(256) void k_att_pre2(
    const unsigned short* __restrict__ xl2, const float* __restrict__ att2,
    float* __restrict__ A2) {
  const int wave = threadIdx.x >> 6;
  const int lane = threadIdx.x & 63;
  const int o8 = lane >> 3;
  const int w = lane & 7;
  const int cb = w * 4;
  const int node = blockIdx.x * 32 + wave * 8 + o8;
  if (node >= N_NODES) return;
  ushortx4 r = *reinterpret_cast<const ushortx4*>(xl2 + (size_t)node * HIDC + cb);
  floatx4 a = *reinterpret_cast<const floatx4*>(att2 + cb);
  float t = 0.f;
#pragma unroll
  for (int c = 0; c < 4; ++c) t = fmaf(bf2f(r[c]), a[c], t);
  t += __shfl_xor(t, 1);
  t += __shfl_xor(t, 2);
  t += __shfl_xor(t, 4);
  if (w == 0) A2[node] = t;
}

// ---------- GAT layer 1 ----------
// leaky(u,0.2) = 0.6u + 0.4|u|  =>  logit = 0.6(A_i + B_j) + 0.4*sum att*|u|
// Plain exp (logits are O(1); clamp +-30 guards overflow). No running max.
// One wave per dst (4/block); halves process alternating edges; pure-sum merge.
// h1 may alias xr1 (own-row read-then-write).
__global__ __launch_bounds__(256) void k_gat1(
    const unsigned short* __restrict__ xl1, const unsigned short* __restrict__ xr1,
    const float* __restrict__ A1,
    const float* __restrict__ att1, const float* __restrict__ b1,
    const int* __restrict__ rowptr, const int* __restrict__ esrc,
    unsigned short* __restrict__ h1) {
  const int wave = threadIdx.x >> 6;
  const int lane = threadIdx.x & 63;
  const int dst = blockIdx.x * 4 + wave;
  if (dst >= N_NODES) return;
  const int h = lane >> 5;
  const int w = lane & 31;
  const int cb = w * 8;
  const int head = w >> 2;

  float xr[8], att[8];
  {
    ushortx8 r = *reinterpret_cast<const ushortx8*>(xr1 + (size_t)dst * C1 + cb);
    floatx4 a0 = *reinterpret_cast<const floatx4*>(att1 + cb);
    floatx4 a1v = *reinterpret_cast<const floatx4*>(att1 + cb + 4);
#pragma unroll
    for (int c = 0; c < 8; ++c) xr[c] = bf2f(r[c]);
#pragma unroll
    for (int c = 0; c < 4; ++c) { att[c] = a0[c]; att[4 + c] = a1v[c]; }
  }
  // B_j = sum att*xr per head
  float B = 0.f;
#pragma unroll
  for (int c = 0; c < 8; ++c) B = fmaf(xr[c], att[c], B);
  B += __shfl_xor(B, 1);
  B += __shfl_xor(B, 2);

  const int beg = rowptr[dst], end = rowptr[dst + 1];
  const int n = end - beg;
  const int* ep = esrc + beg;

  float l = 0.f;
  float acc[8] = {0.f, 0.f, 0.f, 0.f, 0.f, 0.f, 0.f, 0.f};

  int i = h;
  ushortx8 cur = (ushortx8)(unsigned short)0;
  float a1 = 0.f;
  if (i < n) {
    int s = ep[i];
    cur = *reinterpret_cast<const ushortx8*>(xl1 + (size_t)s * C1 + cb);
    a1 = A1[s * HEADS + head];
  }
  while (i < n) {
    const int inext = i + 2;
    ushortx8 nxt = cur;
    float a1n = a1;
    if (inext < n) {
      int s = ep[inext];
      nxt = *reinterpret_cast<const ushortx8*>(xl1 + (size_t)s * C1 + cb);
      a1n = A1[s * HEADS + head];
    }
    float xs[8];
#pragma unroll
    for (int c = 0; c < 8; ++c) xs[c] = bf2f(cur[c]);
    float v = 0.f;
#pragma unroll
    for (int c = 0; c < 8; ++c) {
      float u = xs[c] + xr[c];
      v = fmaf(__builtin_fabsf(u), att[c], v);   // abs = free VOP3 modifier
    }
    v += __shfl_xor(v, 1);
    v += __shfl_xor(v, 2);
    float logit = fmaf(0.4f, v, 0.6f * (a1 + B));
    logit = fminf(fmaxf(logit, -30.f), 30.f);
    const float p = __expf(logit);
    l += p;
#pragma unroll
    for (int c = 0; c < 8; ++c) acc[c] = fmaf(p, xs[c], acc[c]);
    cur = nxt;
    a1 = a1n;
    i = inext;
  }

  // merge halves: pure sums
  l += __shfl_xor(l, 32);
#pragma unroll
  for (int c = 0; c < 8; ++c) acc[c] += __shfl_xor(acc[c], 32);

  if (h == 0) {
    const float inv = 1.f / fmaxf(l, 1e-16f);
    ushortx8 ob;
#pragma unroll
    for (int c = 0; c < 8; ++c) {
      float z = fmaf(acc[c], inv, b1[cb + c]);
      z = z > 0.f ? z : (__expf(z) - 1.f);   // ELU
      ob[c] = f2bf(z);
    }
    *reinterpret_cast<ushortx8*>(h1 + (size_t)dst * C1 + cb) = ob;
  }
}

// ---------- GAT layer 2 (1 head, 32 ch) + final linear [32x16] ----------
__global__ __launch_bounds__(256) void k_gat2(
    const unsigned short* __restrict__ xl2, const unsigned short* __restrict__ xr2,
    const float* __restrict__ A2,
    const float* __restrict__ att2, const float* __restrict__ b2,
    const float* __restrict__ Wlin, const float* __restrict__ blin,
    const int* __restrict__ rowptr, const int* __restrict__ esrc,
    float* __restrict__ out) {
  __shared__ float sh[4][32];
  const int wave = threadIdx.x >> 6;
  const int lane = threadIdx.x & 63;
  const int dst = blockIdx.x * 4 + wave;
  if (dst >= N_NODES) return;
  const int o8 = lane >> 3;
  const int w = lane & 7;
  const int cb = w * 4;

  float xr[4], att[4];
  {
    ushortx4 r = *reinterpret_cast<const ushortx4*>(xr2 + (size_t)dst * HIDC + cb);
    floatx4 a = *reinterpret_cast<const floatx4*>(att2 + cb);
#pragma unroll
    for (int c = 0; c < 4; ++c) { xr[c] = bf2f(r[c]); att[c] = a[c]; }
  }
  float B = 0.f;
#pragma unroll
  for (int c = 0; c < 4; ++c) B = fmaf(xr[c], att[c], B);
  B += __shfl_xor(B, 1);
  B += __shfl_xor(B, 2);
  B += __shfl_xor(B, 4);

  const int beg = rowptr[dst], end = rowptr[dst + 1];
  const int n = end - beg;
  const int* ep = esrc + beg;

  float l = 0.f;
  float acc[4] = {0.f, 0.f, 0.f, 0.f};

  int i = o8;
  ushortx4 cur = (ushortx4)(unsigned short)0;
  float a2 = 0.f;
  if (i < n) {
    int s = ep[i];
    cur = *reinterpret_cast<const ushortx4*>(xl2 + (size_t)s * HIDC + cb);
    a2 = A2[s];
  }
  while (i < n) {
    const int inext = i + 8;
    ushortx4 nxt = cur;
    float a2n = a2;
    if (inext < n) {
      int s = ep[inext];
      nxt = *reinterpret_cast<const ushortx4*>(xl2 + (size_t)s * HIDC + cb);
      a2n = A2[s];
    }
    float xs[4];
#pragma unroll
    for (int c = 0; c < 4; ++c) xs[c] = bf2f(cur[c]);
    float v = 0.f;
#pragma unroll
    for (int c = 0; c < 4; ++c) {
      float u = xs[c] + xr[c];
      v = fmaf(__builtin_fabsf(u), att[c], v);
    }
    v += __shfl_xor(v, 1);
    v += __shfl_xor(v, 2);
    v += __shfl_xor(v, 4);
    float logit = fmaf(0.4f, v, 0.6f * (a2 + B));
    logit = fminf(fmaxf(logit, -30.f), 30.f);
    const float p = __expf(logit);
    l += p;
#pragma unroll
    for (int c = 0; c < 4; ++c) acc[c] = fmaf(p, xs[c], acc[c]);
    cur = nxt;
    a2 = a2n;
    i = inext;
  }

  // merge 8 octets: pure sums
#pragma unroll
  for (int k = 8; k < 64; k <<= 1) {
    l += __shfl_xor(l, k);
#pragma unroll
    for (int c = 0; c < 4; ++c) acc[c] += __shfl_xor(acc[c], k);
  }

  if (o8 == 0) {
    const float inv = 1.f / fmaxf(l, 1e-16f);
#pragma unroll
    for (int c = 0; c < 4; ++c) {
      float z = fmaf(acc[c], inv, b2[cb + c]);
      z = z > 0.f ? z : (__expf(z) - 1.f);   // ELU
      sh[wave][cb + c] = z;
    }
  }
  if (lane < OUTC) {
    float o = blin[lane];
#pragma unroll
    for (int k = 0; k < 32; ++k)
      o = fmaf(sh[wave][k], Wlin[k * OUTC + lane], o);
    out[(size_t)dst * OUTC + lane] = o;
  }
}

static inline int cdiv(int a, int b) { return (a + b - 1) / b; }

extern "C" void kernel_launch(void* const* d_in, const int* in_sizes, int n_in,
                              void* d_out, int out_size, void* d_ws, size_t ws_size,
                              hipStream_t stream) {
  const float* x    = (const float*)d_in[0];
  const int*   ei   = (const int*)d_in[1];
  const float* W1l  = (const float*)d_in[2];
  const float* W1r  = (const float*)d_in[3];
  const float* att1 = (const float*)d_in[4];
  const float* b1   = (const float*)d_in[5];
  const float* W2l  = (const float*)d_in[6];
  const float* W2r  = (const float*)d_in[7];
  const float* att2 = (const float*)d_in[8];
  const float* b2   = (const float*)d_in[9];
  const float* Wlin = (const float*)d_in[10];
  const float* blin = (const float*)d_in[11];
  float* out = (float*)d_out;

  char* w = (char*)d_ws;
  auto alloc = [&](size_t bytes) -> char* {
    char* p = w;
    w += (bytes + 255) & ~(size_t)255;
    return p;
  };
  // region A: xl1 (bf16), later reused for xl2+xr2
  char* regionA = alloc((size_t)N_NODES * C1 * 2);          // 25.6 MB
  unsigned short* xl1 = (unsigned short*)regionA;
  unsigned short* xl2 = (unsigned short*)regionA;                           // 3.2 MB
  unsigned short* xr2 = (unsigned short*)(regionA + (size_t)N_NODES * HIDC * 2 + 256);
  // region B: xr1 aliased with h1 (safe: per-wave own-row read-then-write)
  unsigned short* xr1 = (unsigned short*)alloc((size_t)N_NODES * C1 * 2);   // 25.6 MB
  unsigned short* h1  = xr1;
  unsigned short* W1lT = (unsigned short*)alloc((size_t)D_INF * C1 * 2);
  unsigned short* W1rT = (unsigned short*)alloc((size_t)D_INF * C1 * 2);
  unsigned short* W2lT = (unsigned short*)alloc((size_t)C1 * HIDC * 2);
  unsigned short* W2rT = (unsigned short*)alloc((size_t)C1 * HIDC * 2);
  float* A1   = (float*)alloc((size_t)N_NODES * HEADS * 4);   // 1.6 MB
  float* A2   = (float*)alloc((size_t)N_NODES * 4);           // 0.2 MB
  int* rowptr = (int*)alloc((size_t)(N_NODES + 1) * 4);
  int* cursor = (int*)alloc((size_t)N_NODES * 4);
  int* deg    = (int*)alloc((size_t)N_NODES * 4);
  int* incl   = (int*)alloc((size_t)N_NODES * 4);
  int* bsum   = (int*)alloc((size_t)SCAN_B * 4);
  int* esrc   = (int*)alloc((size_t)E_TOT * 4);
  int* flag   = (int*)alloc(4);

  hipMemsetAsync(deg, 0, (size_t)N_NODES * 4, stream);
  k_detect<<<1, 64, 0, stream>>>(ei, flag);

  k_transpose_all<<<cdiv(2 * D_INF * C1 + 2 * C1 * HIDC, 256), 256, 0, stream>>>(
      W1l, W1r, W2l, W2r, W1lT, W1rT, W2lT, W2rT);

  k_deg<<<cdiv(E_TOT, 256), 256, 0, stream>>>(ei, flag, deg);
  k_scan_blk<<<SCAN_B, 1024, 0, stream>>>(deg, incl, bsum, N_NODES);
  k_scan_top<<<1, 64, 0, stream>>>(bsum, rowptr, SCAN_B);
  k_scan_add<<<SCAN_B, 1024, 0, stream>>>(deg, incl, bsum, rowptr, cursor, N_NODES);
  k_fill<<<cdiv(E_TOT, 256), 256, 0, stream>>>(ei, flag, cursor, esrc);

  const int gblocks = cdiv(N_NODES, 32);   // 1563

  // GEMM1: [50000,128] x ([128,256] x2) -> xl1, xr1
  k_gemm_dual<D_INF, C1><<<gblocks, 256, 0, stream>>>(x, W1lT, W1rT, xl1, xr1, N_NODES);
  k_att_pre1<<<cdiv(N_NODES, 8), 256, 0, stream>>>(xl1, att1, A1);

  k_gat1<<<cdiv(N_NODES, 4), 256, 0, stream>>>(xl1, xr1, A1, att1, b1, rowptr, esrc, h1);

  // GEMM2: [50000,256] x ([256,32] x2) -> xl2, xr2
  k_gemm_dual<C1, HIDC><<<gblocks, 256, 0, stream>>>(h1, W2lT, W2rT, xl2, xr2, N_NODES);
  k_att_pre2<<<cdiv(N_NODES, 32), 256, 0, stream>>>(xl2, att2, A2);

  k_gat2<<<cdiv(N_NODES, 4), 256, 0, stream>>>(xl2, xr2, A2, att2, b2, Wlin, blin,
                                               rowptr, esrc, out);
}

// Round 6
// 286.045 us; speedup vs baseline: 1.0169x; 1.0169x over previous
//
#include <hip/hip_runtime.h>
#include <cstdint>
#include <cstddef>

#define N_NODES 50000
#define N_EDGES 400000
#define E_TOT   (N_EDGES + N_NODES)   // with self-loops
#define D_INF   128
#define C1      256                   // 8 heads * 32
#define HIDC    32
#define OUTC    16
#define HEADS   8
#define SCAN_B  ((N_NODES + 1023) / 1024)   // 49 scan blocks

typedef __bf16 bf16x8 __attribute__((ext_vector_type(8)));
typedef float  floatx4 __attribute__((ext_vector_type(4)));
typedef unsigned int uintx4 __attribute__((ext_vector_type(4)));
typedef unsigned short ushortx8 __attribute__((ext_vector_type(8)));
typedef unsigned short ushortx4 __attribute__((ext_vector_type(4)));

__device__ __forceinline__ unsigned short f2bf(float f) {
  unsigned int u = __builtin_bit_cast(unsigned int, f);
  u += 0x7FFFu + ((u >> 16) & 1u);   // RNE (finite values)
  return (unsigned short)(u >> 16);
}
__device__ __forceinline__ float bf2f(unsigned short u) {
  return __builtin_bit_cast(float, (unsigned int)u << 16);
}

// ---------- edge_index word-width autodetect ----------
__global__ void k_detect(const int* __restrict__ ei, int* __restrict__ flag) {
  __shared__ int s;
  if (threadIdx.x == 0) s = 0;
  __syncthreads();
  atomicOr(&s, ei[2 * threadIdx.x + 1]);
  __syncthreads();
  if (threadIdx.x == 0) *flag = (s == 0) ? 1 : 0;   // 1 = int64
}
__device__ __forceinline__ int ld_src(const int* ei, int f, int e) {
  return f ? ei[2 * e] : ei[e];
}
__device__ __forceinline__ int ld_dst(const int* ei, int f, int e) {
  return f ? ei[2 * (N_EDGES + e)] : ei[N_EDGES + e];
}

// ---------- all 4 weight transposes in one launch (f32 -> bf16, [R][C]->[C][R]) ----------
__global__ void k_transpose_all(const float* __restrict__ W1l, const float* __restrict__ W1r,
                                const float* __restrict__ W2l, const float* __restrict__ W2r,
                                unsigned short* __restrict__ W1lT, unsigned short* __restrict__ W1rT,
                                unsigned short* __restrict__ W2lT, unsigned short* __restrict__ W2rT) {
  int i = blockIdx.x * 256 + threadIdx.x;
  const int S1 = D_INF * C1;          // 32768
  const int S2 = C1 * HIDC;           // 8192
  if (i < S1) {
    int r = i / C1, c = i % C1;
    W1lT[c * D_INF + r] = f2bf(W1l[i]);
  } else if (i < 2 * S1) {
    int j = i - S1; int r = j / C1, c = j % C1;
    W1rT[c * D_INF + r] = f2bf(W1r[j]);
  } else if (i < 2 * S1 + S2) {
    int j = i - 2 * S1; int r = j / HIDC, c = j % HIDC;
    W2lT[c * C1 + r] = f2bf(W2l[j]);
  } else if (i < 2 * S1 + 2 * S2) {
    int j = i - 2 * S1 - S2; int r = j / HIDC, c = j % HIDC;
    W2rT[c * C1 + r] = f2bf(W2r[j]);
  }
}

// ---------- CSR build ----------
__global__ void k_deg(const int* __restrict__ ei, const int* __restrict__ flag,
                      int* __restrict__ deg) {
  int e = blockIdx.x * 256 + threadIdx.x;
  if (e < E_TOT) {
    int dst = (e < N_EDGES) ? ld_dst(ei, *flag, e) : (e - N_EDGES);
    if ((unsigned)dst < N_NODES) atomicAdd(&deg[dst], 1);
  }
}

__global__ __launch_bounds__(1024) void k_scan_blk(
    const int* __restrict__ deg, int* __restrict__ incl,
    int* __restrict__ bsum, int n) {
  __shared__ int sbuf[1024];
  const int t = threadIdx.x;
  const int i = blockIdx.x * 1024 + t;
  const int v = (i < n) ? deg[i] : 0;
  sbuf[t] = v;
  __syncthreads();
  for (int off = 1; off < 1024; off <<= 1) {
    int add = (t >= off) ? sbuf[t - off] : 0;
    __syncthreads();
    sbuf[t] += add;
    __syncthreads();
  }
  if (i < n) incl[i] = sbuf[t];
  if (t == 1023) bsum[blockIdx.x] = sbuf[1023];
}

__global__ void k_scan_top(int* __restrict__ bsum, int* __restrict__ rowptr,
                           int nb) {   // nb <= 64, one wave
  const int lane = threadIdx.x;
  const int v = (lane < nb) ? bsum[lane] : 0;
  int incl = v;
#pragma unroll
  for (int off = 1; off < 64; off <<= 1) {
    int t = __shfl_up(incl, off);
    if (lane >= off) incl += t;
  }
  if (lane < nb) bsum[lane] = incl - v;   // exclusive block offset
  if (lane == 63) rowptr[N_NODES] = incl; // grand total
}

__global__ __launch_bounds__(1024) void k_scan_add(
    const int* __restrict__ deg, const int* __restrict__ incl,
    const int* __restrict__ bsum, int* __restrict__ rowptr,
    int* __restrict__ cursor, int n) {
  const int i = blockIdx.x * 1024 + threadIdx.x;
  if (i < n) {
    const int e = bsum[blockIdx.x] + incl[i] - deg[i];
    rowptr[i] = e;
    cursor[i] = e;
  }
}

__global__ void k_fill(const int* __restrict__ ei, const int* __restrict__ flag,
                       int* __restrict__ cursor, int* __restrict__ esrc) {
  int e = blockIdx.x * 256 + threadIdx.x;
  if (e < E_TOT) {
    int src, dst;
    if (e < N_EDGES) { src = ld_src(ei, *flag, e); dst = ld_dst(ei, *flag, e); }
    else             { src = dst = e - N_EDGES; }
    if ((unsigned)src < N_NODES && (unsigned)dst < N_NODES) {
      int pos = atomicAdd(&cursor[dst], 1);
      esrc[pos] = src;
    }
  }
}

// ---------- A-fragment loaders ----------
__device__ __forceinline__ bf16x8 load8(const unsigned short* p) {
  uintx4 raw = *reinterpret_cast<const uintx4*>(p);
  return __builtin_bit_cast(bf16x8, raw);
}
__device__ __forceinline__ bf16x8 load8(const float* p) {
  floatx4 a = *reinterpret_cast<const floatx4*>(p);
  floatx4 b = *reinterpret_cast<const floatx4*>(p + 4);
  ushortx8 u;
#pragma unroll
  for (int i = 0; i < 4; ++i) { u[i] = f2bf(a[i]); u[4 + i] = f2bf(b[i]); }
  return __builtin_bit_cast(bf16x8, u);
}

// ---------- dual MFMA bf16 GEMM with LDS-staged coalesced epilogue ----------
// block = 4 waves on rows r0..r0+31; wave w computes output (w>>1), column
// tiles (w&1)*NTW..; results staged in LDS then stored as full rows (16B/lane,
// >=64B per transaction -> no HBM write-granule amplification).
// NH>0: additionally compute Adot[n][h] = sum_c att[h*32+c]*C0[n][h*32+c]
// from the staged tile (fuses the A-side attention dot).
template <int K, int NCOLS, int NH, typename AT>
__global__ __launch_bounds__(256) void k_gemm_dual(
    const AT* __restrict__ A,
    const unsigned short* __restrict__ BT0, const unsigned short* __restrict__ BT1,
    unsigned short* __restrict__ C0, unsigned short* __restrict__ C1_,
    const float* __restrict__ att, float* __restrict__ Adot, int M) {
  __shared__ __align__(16) unsigned short tile[2][32][NCOLS];
  const int wave = threadIdx.x >> 6;
  const int lane = threadIdx.x & 63;
  const int lo = lane & 15;   // m for A, n for B, col for C/D
  const int q  = lane >> 4;   // k-chunk quad
  const int r0 = blockIdx.x * 32;
  if (r0 >= M) return;        // whole block exits together (r0 uniform)
  const bool two = (r0 + 16) < M;
  constexpr int KB = K / 32;
  constexpr int NT = NCOLS / 16;
  constexpr int NTW = (NT >= 2) ? NT / 2 : 1;   // tiles per wave

  bf16x8 afrag[2][KB];
#pragma unroll
  for (int kb = 0; kb < KB; ++kb)
    afrag[0][kb] = load8(A + (size_t)(r0 + lo) * K + kb * 32 + q * 8);
  if (two) {
#pragma unroll
    for (int kb = 0; kb < KB; ++kb)
      afrag[1][kb] = load8(A + (size_t)(r0 + 16 + lo) * K + kb * 32 + q * 8);
  }

  const int out_id = wave >> 1;
  const int ntbase = (wave & 1) * NTW;
  const unsigned short* BT = out_id ? BT1 : BT0;

#pragma unroll
  for (int nti = 0; nti < NTW; ++nti) {
    const int nt = ntbase + nti;
    floatx4 acc0 = {0.f, 0.f, 0.f, 0.f};
    floatx4 acc1 = {0.f, 0.f, 0.f, 0.f};
    const unsigned short* bptr = BT + (size_t)(nt * 16 + lo) * K + q * 8;
#pragma unroll
    for (int kb = 0; kb < KB; ++kb) {
      bf16x8 b = load8(bptr + kb * 32);
      acc0 = __builtin_amdgcn_mfma_f32_16x16x32_bf16(afrag[0][kb], b, acc0, 0, 0, 0);
      if (two)
        acc1 = __builtin_amdgcn_mfma_f32_16x16x32_bf16(afrag[1][kb], b, acc1, 0, 0, 0);
    }
    // C/D layout: col = lane&15, row = (lane>>4)*4 + reg   [m89-verified]
    const int col = nt * 16 + lo;
#pragma unroll
    for (int r = 0; r < 4; ++r) {
      tile[out_id][q * 4 + r][col] = f2bf(acc0[r]);
      if (two) tile[out_id][16 + q * 4 + r][col] = f2bf(acc1[r]);
    }
  }
  __syncthreads();

  // cooperative full-row store: 16B per thread-chunk, fully coalesced
  constexpr int SPR = NCOLS / 8;          // 16B segs per row
  constexpr int CPO = 32 * SPR;           // chunks per output
  for (int c = threadIdx.x; c < 2 * CPO; c += 256) {
    const int o = c / CPO;
    const int rem = c % CPO;
    const int row = rem / SPR;
    const int seg = rem % SPR;
    if (r0 + row < M) {
      unsigned short* Cp = o ? C1_ : C0;
      *reinterpret_cast<uintx4*>(Cp + (size_t)(r0 + row) * NCOLS + seg * 8) =
          *reinterpret_cast<const uintx4*>(&tile[o][row][seg * 8]);
    }
  }

  // fused A-side attention dot from staged output-0 tile
  if (NH > 0) {
    const int t = threadIdx.x;
    if (t < 32 * NH) {
      const int row = t / NH;
      const int head = t % NH;
      float s = 0.f;
#pragma unroll
      for (int c = 0; c < 32; ++c)
        s = fmaf(bf2f(tile[0][row][head * 32 + c]), att[head * 32 + c], s);
      if (r0 + row < M) Adot[(size_t)(r0 + row) * NH + head] = s;
    }
  }
}

// ---------- GAT layer 1 ----------
// leaky(u,0.2) = 0.6u + 0.4|u|  =>  logit = 0.6(A_i + B_j) + 0.4*sum att*|u|
// Plain exp (logits are O(1); clamp +-30 guards overflow). No running max.
// One wave per dst (4/block); halves process alternating edges; pure-sum merge.
// h1 may alias xr1 (own-row read-then-write).
__global__ __launch_bounds__(256) void k_gat1(
    const unsigned short* __restrict__ xl1, const unsigned short* __restrict__ xr1,
    const float* __restrict__ A1,
    const float* __restrict__ att1, const float* __restrict__ b1,
    const int* __restrict__ rowptr, const int* __restrict__ esrc,
    unsigned short* __restrict__ h1) {
  const int wave = threadIdx.x >> 6;
  const int lane = threadIdx.x & 63;
  const int dst = blockIdx.x * 4 + wave;
  if (dst >= N_NODES) return;
  const int h = lane >> 5;
  const int w = lane & 31;
  const int cb = w * 8;
  const int head = w >> 2;

  float xr[8], att[8];
  {
    ushortx8 r = *reinterpret_cast<const ushortx8*>(xr1 + (size_t)dst * C1 + cb);
    floatx4 a0 = *reinterpret_cast<const floatx4*>(att1 + cb);
    floatx4 a1v = *reinterpret_cast<const floatx4*>(att1 + cb + 4);
#pragma unroll
    for (int c = 0; c < 8; ++c) xr[c] = bf2f(r[c]);
#pragma unroll
    for (int c = 0; c < 4; ++c) { att[c] = a0[c]; att[4 + c] = a1v[c]; }
  }
  // B_j = sum att*xr per head
  float B = 0.f;
#pragma unroll
  for (int c = 0; c < 8; ++c) B = fmaf(xr[c], att[c], B);
  B += __shfl_xor(B, 1);
  B += __shfl_xor(B, 2);

  const int beg = rowptr[dst], end = rowptr[dst + 1];
  const int n = end - beg;
  const int* ep = esrc + beg;

  float l = 0.f;
  float acc[8] = {0.f, 0.f, 0.f, 0.f, 0.f, 0.f, 0.f, 0.f};

  int i = h;
  ushortx8 cur = (ushortx8)(unsigned short)0;
  float a1 = 0.f;
  if (i < n) {
    int s = ep[i];
    cur = *reinterpret_cast<const ushortx8*>(xl1 + (size_t)s * C1 + cb);
    a1 = A1[s * HEADS + head];
  }
  while (i < n) {
    const int inext = i + 2;
    ushortx8 nxt = cur;
    float a1n = a1;
    if (inext < n) {
      int s = ep[inext];
      nxt = *reinterpret_cast<const ushortx8*>(xl1 + (size_t)s * C1 + cb);
      a1n = A1[s * HEADS + head];
    }
    float xs[8];
#pragma unroll
    for (int c = 0; c < 8; ++c) xs[c] = bf2f(cur[c]);
    float v = 0.f;
#pragma unroll
    for (int c = 0; c < 8; ++c) {
      float u = xs[c] + xr[c];
      v = fmaf(__builtin_fabsf(u), att[c], v);   // abs = free VOP3 modifier
    }
    v += __shfl_xor(v, 1);
    v += __shfl_xor(v, 2);
    float logit = fmaf(0.4f, v, 0.6f * (a1 + B));
    logit = fminf(fmaxf(logit, -30.f), 30.f);
    const float p = __expf(logit);
    l += p;
#pragma unroll
    for (int c = 0; c < 8; ++c) acc[c] = fmaf(p, xs[c], acc[c]);
    cur = nxt;
    a1 = a1n;
    i = inext;
  }

  // merge halves: pure sums
  l += __shfl_xor(l, 32);
#pragma unroll
  for (int c = 0; c < 8; ++c) acc[c] += __shfl_xor(acc[c], 32);

  if (h == 0) {
    const float inv = 1.f / fmaxf(l, 1e-16f);
    ushortx8 ob;
#pragma unroll
    for (int c = 0; c < 8; ++c) {
      float z = fmaf(acc[c], inv, b1[cb + c]);
      z = z > 0.f ? z : (__expf(z) - 1.f);   // ELU
      ob[c] = f2bf(z);
    }
    *reinterpret_cast<ushortx8*>(h1 + (size_t)dst * C1 + cb) = ob;
  }
}

// ---------- GAT layer 2 (1 head, 32 ch) + final linear [32x16] ----------
__global__ __launch_bounds__(256) void k_gat2(
    const unsigned short* __restrict__ xl2, const unsigned short* __restrict__ xr2,
    const float* __restrict__ A2,
    const float* __restrict__ att2, const float* __restrict__ b2,
    const float* __restrict__ Wlin, const float* __restrict__ blin,
    const int* __restrict__ rowptr, const int* __restrict__ esrc,
    float* __restrict__ out) {
  __shared__ float sh[4][32];
  const int wave = threadIdx.x >> 6;
  const int lane = threadIdx.x & 63;
  const int dst = blockIdx.x * 4 + wave;
  if (dst >= N_NODES) return;
  const int o8 = lane >> 3;
  const int w = lane & 7;
  const int cb = w * 4;

  float xr[4], att[4];
  {
    ushortx4 r = *reinterpret_cast<const ushortx4*>(xr2 + (size_t)dst * HIDC + cb);
    floatx4 a = *reinterpret_cast<const floatx4*>(att2 + cb);
#pragma unroll
    for (int c = 0; c < 4; ++c) { xr[c] = bf2f(r[c]); att[c] = a[c]; }
  }
  float B = 0.f;
#pragma unroll
  for (int c = 0; c < 4; ++c) B = fmaf(xr[c], att[c], B);
  B += __shfl_xor(B, 1);
  B += __shfl_xor(B, 2);
  B += __shfl_xor(B, 4);

  const int beg = rowptr[dst], end = rowptr[dst + 1];
  const int n = end - beg;
  const int* ep = esrc + beg;

  float l = 0.f;
  float acc[4] = {0.f, 0.f, 0.f, 0.f};

  int i = o8;
  ushortx4 cur = (ushortx4)(unsigned short)0;
  float a2 = 0.f;
  if (i < n) {
    int s = ep[i];
    cur = *reinterpret_cast<const ushortx4*>(xl2 + (size_t)s * HIDC + cb);
    a2 = A2[s];
  }
  while (i < n) {
    const int inext = i + 8;
    ushortx4 nxt = cur;
    float a2n = a2;
    if (inext < n) {
      int s = ep[inext];
      nxt = *reinterpret_cast<const ushortx4*>(xl2 + (size_t)s * HIDC + cb);
      a2n = A2[s];
    }
    float xs[4];
#pragma unroll
    for (int c = 0; c < 4; ++c) xs[c] = bf2f(cur[c]);
    float v = 0.f;
#pragma unroll
    for (int c = 0; c < 4; ++c) {
      float u = xs[c] + xr[c];
      v = fmaf(__builtin_fabsf(u), att[c], v);
    }
    v += __shfl_xor(v, 1);
    v += __shfl_xor(v, 2);
    v += __shfl_xor(v, 4);
    float logit = fmaf(0.4f, v, 0.6f * (a2 + B));
    logit = fminf(fmaxf(logit, -30.f), 30.f);
    const float p = __expf(logit);
    l += p;
#pragma unroll
    for (int c = 0; c < 4; ++c) acc[c] = fmaf(p, xs[c], acc[c]);
    cur = nxt;
    a2 = a2n;
    i = inext;
  }

  // merge 8 octets: pure sums
#pragma unroll
  for (int k = 8; k < 64; k <<= 1) {
    l += __shfl_xor(l, k);
#pragma unroll
    for (int c = 0; c < 4; ++c) acc[c] += __shfl_xor(acc[c], k);
  }

  if (o8 == 0) {
    const float inv = 1.f / fmaxf(l, 1e-16f);
#pragma unroll
    for (int c = 0; c < 4; ++c) {
      float z = fmaf(acc[c], inv, b2[cb + c]);
      z = z > 0.f ? z : (__expf(z) - 1.f);   // ELU
      sh[wave][cb + c] = z;
    }
  }
  if (lane < OUTC) {
    float o = blin[lane];
#pragma unroll
    for (int k = 0; k < 32; ++k)
      o = fmaf(sh[wave][k], Wlin[k * OUTC + lane], o);
    out[(size_t)dst * OUTC + lane] = o;
  }
}

static inline int cdiv(int a, int b) { return (a + b - 1) / b; }

extern "C" void kernel_launch(void* const* d_in, const int* in_sizes, int n_in,
                              void* d_out, int out_size, void* d_ws, size_t ws_size,
                              hipStream_t stream) {
  const float* x    = (const float*)d_in[0];
  const int*   ei   = (const int*)d_in[1];
  const float* W1l  = (const float*)d_in[2];
  const float* W1r  = (const float*)d_in[3];
  const float* att1 = (const float*)d_in[4];
  const float* b1   = (const float*)d_in[5];
  const float* W2l  = (const float*)d_in[6];
  const float* W2r  = (const float*)d_in[7];
  const float* att2 = (const float*)d_in[8];
  const float* b2   = (const float*)d_in[9];
  const float* Wlin = (const float*)d_in[10];
  const float* blin = (const float*)d_in[11];
  float* out = (float*)d_out;

  char* w = (char*)d_ws;
  auto alloc = [&](size_t bytes) -> char* {
    char* p = w;
    w += (bytes + 255) & ~(size_t)255;
    return p;
  };
  // region A: xl1 (bf16), later reused for xl2+xr2
  char* regionA = alloc((size_t)N_NODES * C1 * 2);          // 25.6 MB
  unsigned short* xl1 = (unsigned short*)regionA;
  unsigned short* xl2 = (unsigned short*)regionA;                           // 3.2 MB
  unsigned short* xr2 = (unsigned short*)(regionA + (size_t)N_NODES * HIDC * 2 + 256);
  // region B: xr1 aliased with h1 (safe: per-wave own-row read-then-write)
  unsigned short* xr1 = (unsigned short*)alloc((size_t)N_NODES * C1 * 2);   // 25.6 MB
  unsigned short* h1  = xr1;
  unsigned short* W1lT = (unsigned short*)alloc((size_t)D_INF * C1 * 2);
  unsigned short* W1rT = (unsigned short*)alloc((size_t)D_INF * C1 * 2);
  unsigned short* W2lT = (unsigned short*)alloc((size_t)C1 * HIDC * 2);
  unsigned short* W2rT = (unsigned short*)alloc((size_t)C1 * HIDC * 2);
  float* A1   = (float*)alloc((size_t)N_NODES * HEADS * 4);   // 1.6 MB
  float* A2   = (float*)alloc((size_t)N_NODES * 4);           // 0.2 MB
  int* rowptr = (int*)alloc((size_t)(N_NODES + 1) * 4);
  int* cursor = (int*)alloc((size_t)N_NODES * 4);
  int* deg    = (int*)alloc((size_t)N_NODES * 4);
  int* incl   = (int*)alloc((size_t)N_NODES * 4);
  int* bsum   = (int*)alloc((size_t)SCAN_B * 4);
  int* esrc   = (int*)alloc((size_t)E_TOT * 4);
  int* flag   = (int*)alloc(4);

  hipMemsetAsync(deg, 0, (size_t)N_NODES * 4, stream);
  k_detect<<<1, 64, 0, stream>>>(ei, flag);

  k_transpose_all<<<cdiv(2 * D_INF * C1 + 2 * C1 * HIDC, 256), 256, 0, stream>>>(
      W1l, W1r, W2l, W2r, W1lT, W1rT, W2lT, W2rT);

  k_deg<<<cdiv(E_TOT, 256), 256, 0, stream>>>(ei, flag, deg);
  k_scan_blk<<<SCAN_B, 1024, 0, stream>>>(deg, incl, bsum, N_NODES);
  k_scan_top<<<1, 64, 0, stream>>>(bsum, rowptr, SCAN_B);
  k_scan_add<<<SCAN_B, 1024, 0, stream>>>(deg, incl, bsum, rowptr, cursor, N_NODES);
  k_fill<<<cdiv(E_TOT, 256), 256, 0, stream>>>(ei, flag, cursor, esrc);

  const int gblocks = cdiv(N_NODES, 32);   // 1563

  // GEMM1: [50000,128] x ([128,256] x2) -> xl1, xr1 ; fused A1 dot
  k_gemm_dual<D_INF, C1, HEADS><<<gblocks, 256, 0, stream>>>(
      x, W1lT, W1rT, xl1, xr1, att1, A1, N_NODES);

  k_gat1<<<cdiv(N_NODES, 4), 256, 0, stream>>>(xl1, xr1, A1, att1, b1, rowptr, esrc, h1);

  // GEMM2: [50000,256] x ([256,32] x2) -> xl2, xr2 ; fused A2 dot
  k_gemm_dual<C1, HIDC, 1><<<gblocks, 256, 0, stream>>>(
      h1, W2lT, W2rT, xl2, xr2, att2, A2, N_NODES);

  k_gat2<<<cdiv(N_NODES, 4), 256, 0, stream>>>(xl2, xr2, A2, att2, b2, Wlin, blin,
                                               rowptr, esrc, out);
}